// Round 1
// baseline (101.898 us; speedup 1.0000x reference)
//
#include <hip/hip_runtime.h>
#include <hip/hip_bf16.h>

#define VOCAB 100000
#define EMB 128
#define EPS 1e-12f

typedef __attribute__((ext_vector_type(8))) unsigned short ushort8_t;

__device__ __forceinline__ float bf2f(unsigned short u) {
    union { unsigned int i; float f; } c;
    c.i = ((unsigned int)u) << 16;
    return c.f;
}

__device__ __forceinline__ unsigned short f2bf(float f) {
    __hip_bfloat16 h = __float2bfloat16(f);
    return __builtin_bit_cast(unsigned short, h);
}

// Phase 1: build normalized transposed table nt[v][j] (bf16), v in [0,VOCAB).
// nt[v][j] = (W[j][v] + b[j]) / max(||W[:,v]+b||, EPS)
__global__ __launch_bounds__(256) void build_table_kernel(
    const float* __restrict__ W, const float* __restrict__ b,
    unsigned short* __restrict__ nt) {
    int v = blockIdx.x * 256 + threadIdx.x;
    if (v >= VOCAB) return;

    float ss = 0.f;
#pragma unroll 16
    for (int j = 0; j < EMB; ++j) {
        float e = W[(size_t)j * VOCAB + v] + b[j];
        ss = fmaf(e, e, ss);
    }
    float inv = 1.0f / fmaxf(sqrtf(ss), EPS);

    unsigned short* row = nt + (size_t)v * EMB;
#pragma unroll
    for (int j0 = 0; j0 < EMB; j0 += 8) {
        ushort8_t pack;
#pragma unroll
        for (int k = 0; k < 8; ++k) {
            float e = (W[(size_t)(j0 + k) * VOCAB + v] + b[j0 + k]) * inv;
            pack[k] = f2bf(e);
        }
        *reinterpret_cast<ushort8_t*>(row + j0) = pack;
    }
}

// Phase 2: 16 lanes per sample. Lane l handles elements [l*8, l*8+8).
// Gathers the two normalized rows (256B contiguous per row per group),
// h = nx*ny, dots with w1/w2, 16-lane reduce, sigmoid, write out1/out2.
__global__ __launch_bounds__(256) void fused_gather_kernel(
    const int* __restrict__ x, const int* __restrict__ y,
    const unsigned short* __restrict__ nt,
    const float* __restrict__ w1, const float* __restrict__ b1p,
    const float* __restrict__ w2, const float* __restrict__ b2p,
    float* __restrict__ out, int n) {
    const int tid = threadIdx.x;
    const int lane16 = tid & 15;

    float w1f[8], w2f[8];
#pragma unroll
    for (int k = 0; k < 8; ++k) {
        w1f[k] = w1[lane16 * 8 + k];
        w2f[k] = w2[lane16 * 8 + k];
    }
    const float bb1 = *b1p;
    const float bb2 = *b2p;

    const int group   = blockIdx.x * (blockDim.x >> 4) + (tid >> 4);
    const int ngroups = gridDim.x * (blockDim.x >> 4);

    for (int i = group; i < n; i += ngroups) {
        const int ix = x[i];
        const int iy = y[i];
        ushort8_t vx = *reinterpret_cast<const ushort8_t*>(nt + (size_t)ix * EMB + lane16 * 8);
        ushort8_t vy = *reinterpret_cast<const ushort8_t*>(nt + (size_t)iy * EMB + lane16 * 8);

        float d1 = 0.f, d2 = 0.f;
#pragma unroll
        for (int k = 0; k < 8; ++k) {
            float h = bf2f(vx[k]) * bf2f(vy[k]);
            d1 = fmaf(h, w1f[k], d1);
            d2 = fmaf(h, w2f[k], d2);
        }
        // reduce across the 16-lane group (xor masks < 16 stay in-group)
#pragma unroll
        for (int off = 8; off >= 1; off >>= 1) {
            d1 += __shfl_xor(d1, off, 64);
            d2 += __shfl_xor(d2, off, 64);
        }
        if (lane16 == 0) {
            out[i]     = 1.f / (1.f + __expf(-(d1 + bb1)));
            out[n + i] = 1.f / (1.f + __expf(-(d2 + bb2)));
        }
    }
}

// Fallback (only if ws is too small for the table): gather W columns directly.
__global__ __launch_bounds__(256) void fused_direct_kernel(
    const int* __restrict__ x, const int* __restrict__ y,
    const float* __restrict__ W, const float* __restrict__ b,
    const float* __restrict__ w1, const float* __restrict__ b1p,
    const float* __restrict__ w2, const float* __restrict__ b2p,
    float* __restrict__ out, int n) {
    const int tid = threadIdx.x;
    const int lane16 = tid & 15;

    float bl[8], w1f[8], w2f[8];
#pragma unroll
    for (int k = 0; k < 8; ++k) {
        bl[k]  = b[lane16 * 8 + k];
        w1f[k] = w1[lane16 * 8 + k];
        w2f[k] = w2[lane16 * 8 + k];
    }
    const float bb1 = *b1p;
    const float bb2 = *b2p;

    const int group   = blockIdx.x * (blockDim.x >> 4) + (tid >> 4);
    const int ngroups = gridDim.x * (blockDim.x >> 4);

    for (int i = group; i < n; i += ngroups) {
        const int ix = x[i];
        const int iy = y[i];
        float ex[8], ey[8];
        float ssx = 0.f, ssy = 0.f;
#pragma unroll
        for (int k = 0; k < 8; ++k) {
            int j = lane16 * 8 + k;
            ex[k] = W[(size_t)j * VOCAB + ix] + bl[k];
            ey[k] = W[(size_t)j * VOCAB + iy] + bl[k];
            ssx = fmaf(ex[k], ex[k], ssx);
            ssy = fmaf(ey[k], ey[k], ssy);
        }
#pragma unroll
        for (int off = 8; off >= 1; off >>= 1) {
            ssx += __shfl_xor(ssx, off, 64);
            ssy += __shfl_xor(ssy, off, 64);
        }
        float invx = 1.0f / fmaxf(sqrtf(ssx), EPS);
        float invy = 1.0f / fmaxf(sqrtf(ssy), EPS);

        float d1 = 0.f, d2 = 0.f;
#pragma unroll
        for (int k = 0; k < 8; ++k) {
            float h = (ex[k] * invx) * (ey[k] * invy);
            d1 = fmaf(h, w1f[k], d1);
            d2 = fmaf(h, w2f[k], d2);
        }
#pragma unroll
        for (int off = 8; off >= 1; off >>= 1) {
            d1 += __shfl_xor(d1, off, 64);
            d2 += __shfl_xor(d2, off, 64);
        }
        if (lane16 == 0) {
            out[i]     = 1.f / (1.f + __expf(-(d1 + bb1)));
            out[n + i] = 1.f / (1.f + __expf(-(d2 + bb2)));
        }
    }
}

extern "C" void kernel_launch(void* const* d_in, const int* in_sizes, int n_in,
                              void* d_out, int out_size, void* d_ws, size_t ws_size,
                              hipStream_t stream) {
    const int*   x  = (const int*)d_in[0];
    const int*   y  = (const int*)d_in[1];
    const float* W  = (const float*)d_in[2];
    const float* b  = (const float*)d_in[3];
    const float* w1 = (const float*)d_in[4];
    const float* b1 = (const float*)d_in[5];
    const float* w2 = (const float*)d_in[6];
    const float* b2 = (const float*)d_in[7];
    float* out = (float*)d_out;
    const int n = in_sizes[0];

    const size_t table_bytes = (size_t)VOCAB * EMB * sizeof(unsigned short);

    // 16 lanes per sample, 256 threads/block -> 16 samples per block-iteration
    int ngroups = (n + 15) / 16;
    int blocks  = (ngroups + 15) / 16;
    if (blocks > 8192) blocks = 8192;

    if (ws_size >= table_bytes) {
        unsigned short* nt = (unsigned short*)d_ws;
        build_table_kernel<<<(VOCAB + 255) / 256, 256, 0, stream>>>(W, b, nt);
        fused_gather_kernel<<<blocks, 256, 0, stream>>>(x, y, nt, w1, b1, w2, b2, out, n);
    } else {
        fused_direct_kernel<<<blocks, 256, 0, stream>>>(x, y, W, b, w1, b1, w2, b2, out, n);
    }
}

// Round 2
// 91.735 us; speedup vs baseline: 1.1108x; 1.1108x over previous
//
#include <hip/hip_runtime.h>
#include <hip/hip_bf16.h>
#include <hip/hip_fp16.h>

#define VOCAB 100000
#define EMB 128
#define EPS 1e-12f

typedef __attribute__((ext_vector_type(4))) unsigned int uint4_t;

__device__ __forceinline__ float bflo(unsigned int u) {
    union { unsigned int i; float f; } c; c.i = u << 16; return c.f;
}
__device__ __forceinline__ float bfhi(unsigned int u) {
    union { unsigned int i; float f; } c; c.i = u & 0xffff0000u; return c.f;
}
__device__ __forceinline__ unsigned int f2bf(float f) {
    __hip_bfloat16 h = __float2bfloat16(f);
    return (unsigned int)__builtin_bit_cast(unsigned short, h);
}

// Phase 1 (single pass over W): row v of nt = bf16( (W[:,v]+b) / max(||W[:,v]+b||, EPS) )
// Pre-norm e stashed as f16 pairs in registers (64 u32) while accumulating sum-squares.
__global__ __launch_bounds__(256) void build_table_kernel(
    const float* __restrict__ W, const float* __restrict__ b,
    unsigned int* __restrict__ nt) {
    int v = blockIdx.x * 256 + threadIdx.x;
    if (v >= VOCAB) return;

    float ss = 0.f;
    unsigned int stash[64];
#pragma unroll
    for (int j = 0; j < 64; ++j) {
        float e0 = W[(size_t)(2 * j) * VOCAB + v] + b[2 * j];
        float e1 = W[(size_t)(2 * j + 1) * VOCAB + v] + b[2 * j + 1];
        ss = fmaf(e0, e0, ss);
        ss = fmaf(e1, e1, ss);
        __half2 h2 = __floats2half2_rn(e0, e1);
        stash[j] = __builtin_bit_cast(unsigned int, h2);
    }
    float inv = 1.0f / fmaxf(sqrtf(ss), EPS);
#pragma unroll
    for (int j = 0; j < 64; ++j) {
        __half2 h2 = __builtin_bit_cast(__half2, stash[j]);
        float e0 = __low2float(h2) * inv;
        float e1 = __high2float(h2) * inv;
        stash[j] = f2bf(e0) | (f2bf(e1) << 16);
    }
    uint4_t* row = (uint4_t*)(nt + (size_t)v * 64);
#pragma unroll
    for (int q = 0; q < 16; ++q) {
        uint4_t pk;
        pk[0] = stash[4 * q + 0];
        pk[1] = stash[4 * q + 1];
        pk[2] = stash[4 * q + 2];
        pk[3] = stash[4 * q + 3];
        row[q] = pk;
    }
}

// Phase 2: 8 lanes per sample, 16 elements (32B) per lane per row.
// Index prefetch one iteration ahead; 4 outstanding 16B gathers per lane-iter.
__global__ __launch_bounds__(256) void fused_gather8_kernel(
    const int* __restrict__ x, const int* __restrict__ y,
    const unsigned int* __restrict__ nt,
    const float* __restrict__ w1, const float* __restrict__ b1p,
    const float* __restrict__ w2, const float* __restrict__ b2p,
    float* __restrict__ out, int n) {
    const int tid = threadIdx.x;
    const int l = tid & 7;
    const int group = blockIdx.x * 32 + (tid >> 3);
    const int ngroups = gridDim.x * 32;

    // lane l owns elements [16l, 16l+16)
    float w1f[16], w2f[16];
#pragma unroll
    for (int k = 0; k < 16; ++k) {
        w1f[k] = w1[l * 16 + k];
        w2f[k] = w2[l * 16 + k];
    }
    const float bb1 = *b1p, bb2 = *b2p;

    int i = group;
    int ix = 0, iy = 0;
    if (i < n) { ix = x[i]; iy = y[i]; }
    while (i < n) {
        const int inext = i + ngroups;
        int ixn = 0, iyn = 0;
        if (inext < n) { ixn = x[inext]; iyn = y[inext]; }

        const uint4_t* px = (const uint4_t*)(nt + (size_t)ix * 64) + 2 * l;
        const uint4_t* py = (const uint4_t*)(nt + (size_t)iy * 64) + 2 * l;
        uint4_t vx0 = px[0], vx1 = px[1];
        uint4_t vy0 = py[0], vy1 = py[1];

        float d1 = 0.f, d2 = 0.f;
#pragma unroll
        for (int q = 0; q < 4; ++q) {
            {
                unsigned int ux = vx0[q], uy = vy0[q];
                float h0 = bflo(ux) * bflo(uy);
                float h1 = bfhi(ux) * bfhi(uy);
                d1 = fmaf(h0, w1f[2 * q], d1);
                d2 = fmaf(h0, w2f[2 * q], d2);
                d1 = fmaf(h1, w1f[2 * q + 1], d1);
                d2 = fmaf(h1, w2f[2 * q + 1], d2);
            }
            {
                unsigned int ux = vx1[q], uy = vy1[q];
                float h0 = bflo(ux) * bflo(uy);
                float h1 = bfhi(ux) * bfhi(uy);
                d1 = fmaf(h0, w1f[8 + 2 * q], d1);
                d2 = fmaf(h0, w2f[8 + 2 * q], d2);
                d1 = fmaf(h1, w1f[8 + 2 * q + 1], d1);
                d2 = fmaf(h1, w2f[8 + 2 * q + 1], d2);
            }
        }
        // butterfly over the 8-lane group
#pragma unroll
        for (int off = 1; off <= 4; off <<= 1) {
            d1 += __shfl_xor(d1, off, 64);
            d2 += __shfl_xor(d2, off, 64);
        }
        if (l == 0)      out[i]     = 1.f / (1.f + __expf(-(d1 + bb1)));
        else if (l == 1) out[n + i] = 1.f / (1.f + __expf(-(d2 + bb2)));

        i = inext; ix = ixn; iy = iyn;
    }
}

// Fallback (ws too small for table): gather W columns directly, G=16.
__global__ __launch_bounds__(256) void fused_direct_kernel(
    const int* __restrict__ x, const int* __restrict__ y,
    const float* __restrict__ W, const float* __restrict__ b,
    const float* __restrict__ w1, const float* __restrict__ b1p,
    const float* __restrict__ w2, const float* __restrict__ b2p,
    float* __restrict__ out, int n) {
    const int tid = threadIdx.x;
    const int lane16 = tid & 15;

    float bl[8], w1f[8], w2f[8];
#pragma unroll
    for (int k = 0; k < 8; ++k) {
        bl[k]  = b[lane16 * 8 + k];
        w1f[k] = w1[lane16 * 8 + k];
        w2f[k] = w2[lane16 * 8 + k];
    }
    const float bb1 = *b1p, bb2 = *b2p;

    const int group   = blockIdx.x * (blockDim.x >> 4) + (tid >> 4);
    const int ngroups = gridDim.x * (blockDim.x >> 4);

    for (int i = group; i < n; i += ngroups) {
        const int ix = x[i];
        const int iy = y[i];
        float ex[8], ey[8];
        float ssx = 0.f, ssy = 0.f;
#pragma unroll
        for (int k = 0; k < 8; ++k) {
            int j = lane16 * 8 + k;
            ex[k] = W[(size_t)j * VOCAB + ix] + bl[k];
            ey[k] = W[(size_t)j * VOCAB + iy] + bl[k];
            ssx = fmaf(ex[k], ex[k], ssx);
            ssy = fmaf(ey[k], ey[k], ssy);
        }
#pragma unroll
        for (int off = 8; off >= 1; off >>= 1) {
            ssx += __shfl_xor(ssx, off, 64);
            ssy += __shfl_xor(ssy, off, 64);
        }
        float invx = 1.0f / fmaxf(sqrtf(ssx), EPS);
        float invy = 1.0f / fmaxf(sqrtf(ssy), EPS);

        float d1 = 0.f, d2 = 0.f;
#pragma unroll
        for (int k = 0; k < 8; ++k) {
            float h = (ex[k] * invx) * (ey[k] * invy);
            d1 = fmaf(h, w1f[k], d1);
            d2 = fmaf(h, w2f[k], d2);
        }
#pragma unroll
        for (int off = 8; off >= 1; off >>= 1) {
            d1 += __shfl_xor(d1, off, 64);
            d2 += __shfl_xor(d2, off, 64);
        }
        if (lane16 == 0) {
            out[i]     = 1.f / (1.f + __expf(-(d1 + bb1)));
            out[n + i] = 1.f / (1.f + __expf(-(d2 + bb2)));
        }
    }
}

extern "C" void kernel_launch(void* const* d_in, const int* in_sizes, int n_in,
                              void* d_out, int out_size, void* d_ws, size_t ws_size,
                              hipStream_t stream) {
    const int*   x  = (const int*)d_in[0];
    const int*   y  = (const int*)d_in[1];
    const float* W  = (const float*)d_in[2];
    const float* b  = (const float*)d_in[3];
    const float* w1 = (const float*)d_in[4];
    const float* b1 = (const float*)d_in[5];
    const float* w2 = (const float*)d_in[6];
    const float* b2 = (const float*)d_in[7];
    float* out = (float*)d_out;
    const int n = in_sizes[0];

    const size_t table_bytes = (size_t)VOCAB * EMB * sizeof(unsigned short);

    if (ws_size >= table_bytes) {
        unsigned int* nt = (unsigned int*)d_ws;
        build_table_kernel<<<(VOCAB + 255) / 256, 256, 0, stream>>>(W, b, nt);
        int blocks = 4096;
        if ((size_t)n < (size_t)blocks * 32) blocks = (n + 31) / 32;
        if (blocks < 1) blocks = 1;
        fused_gather8_kernel<<<blocks, 256, 0, stream>>>(x, y, nt, w1, b1, w2, b2, out, n);
    } else {
        int ngroups = (n + 15) / 16;
        int blocks  = (ngroups + 15) / 16;
        if (blocks > 8192) blocks = 8192;
        if (blocks < 1) blocks = 1;
        fused_direct_kernel<<<blocks, 256, 0, stream>>>(x, y, W, b, w1, b1, w2, b2, out, n);
    }
}

// Round 3
// 54.951 us; speedup vs baseline: 1.8544x; 1.6694x over previous
//
#include <hip/hip_runtime.h>
#include <hip/hip_bf16.h>
#include <hip/hip_fp16.h>

#define VOCAB 100000
#define EMB 128
#define EPS 1e-12f

typedef __attribute__((ext_vector_type(4))) unsigned int uint4_t;
typedef __attribute__((ext_vector_type(2))) float float2_t;

__device__ __forceinline__ float sigmoidf_(float z) {
    return 1.f / (1.f + __expf(-z));
}

// Phase 1 (single pass over W): row v of nt = fp8_e4m3( (W[:,v]+b) / max(||W[:,v]+b||, EPS) )
// Pre-norm e stashed as f16 pairs in registers; final quantization is the fp8 step
// (2^-4 rel) so the f16 intermediate (2^-11 rel) is invisible.
__global__ __launch_bounds__(256) void build_table_fp8_kernel(
    const float* __restrict__ W, const float* __restrict__ b,
    unsigned int* __restrict__ nt) {
    int v = blockIdx.x * 256 + threadIdx.x;
    if (v >= VOCAB) return;

    float ss = 0.f;
    unsigned int stash[64];
#pragma unroll
    for (int j = 0; j < 64; ++j) {
        float e0 = W[(size_t)(2 * j) * VOCAB + v] + b[2 * j];
        float e1 = W[(size_t)(2 * j + 1) * VOCAB + v] + b[2 * j + 1];
        ss = fmaf(e0, e0, ss);
        ss = fmaf(e1, e1, ss);
        stash[j] = __builtin_bit_cast(unsigned int, __floats2half2_rn(e0, e1));
    }
    float inv = 1.0f / fmaxf(sqrtf(ss), EPS);

    unsigned int packed[32];
#pragma unroll
    for (int j = 0; j < 32; ++j) {
        __half2 h0 = __builtin_bit_cast(__half2, stash[2 * j]);
        __half2 h1 = __builtin_bit_cast(__half2, stash[2 * j + 1]);
        float e0 = __low2float(h0) * inv, e1 = __high2float(h0) * inv;
        float e2 = __low2float(h1) * inv, e3 = __high2float(h1) * inv;
        unsigned int u = __builtin_amdgcn_cvt_pk_fp8_f32(e0, e1, 0u, false);
        u = __builtin_amdgcn_cvt_pk_fp8_f32(e2, e3, u, true);
        packed[j] = u;
    }
    uint4_t* row = (uint4_t*)(nt + (size_t)v * 32);
#pragma unroll
    for (int q = 0; q < 8; ++q) {
        uint4_t pk;
        pk[0] = packed[4 * q + 0];
        pk[1] = packed[4 * q + 1];
        pk[2] = packed[4 * q + 2];
        pk[3] = packed[4 * q + 3];
        row[q] = pk;
    }
}

// Phase 2: fp8 table, 8 lanes per sample (row = 128B = 1 cache line,
// 16B = 16 elems per lane), 2 samples per iteration + index prefetch.
__global__ __launch_bounds__(256) void fused_gather_fp8_kernel(
    const int* __restrict__ x, const int* __restrict__ y,
    const unsigned int* __restrict__ nt,
    const float* __restrict__ w1, const float* __restrict__ b1p,
    const float* __restrict__ w2, const float* __restrict__ b2p,
    float* __restrict__ out, int n) {
    const int tid = threadIdx.x;
    const int l = tid & 7;
    const int group = blockIdx.x * 32 + (tid >> 3);
    const int ng = gridDim.x * 32;

    // lane l owns elements [16l, 16l+16)
    float w1f[16], w2f[16];
#pragma unroll
    for (int k = 0; k < 16; ++k) {
        w1f[k] = w1[l * 16 + k];
        w2f[k] = w2[l * 16 + k];
    }
    const float bb1 = *b1p, bb2 = *b2p;

    const uint4_t* base = (const uint4_t*)nt;  // row v = base[v*8 .. v*8+7]

    int i0 = group, i1 = group + ng;
    int c0 = (i0 < n) ? i0 : 0;
    int c1 = (i1 < n) ? i1 : 0;
    int ix0 = x[c0], iy0 = y[c0];
    int ix1 = x[c1], iy1 = y[c1];

    while (i0 < n) {
        // issue row gathers for both slots (4 x 16B in flight per lane)
        uint4_t vx0 = base[(size_t)ix0 * 8 + l];
        uint4_t vy0 = base[(size_t)iy0 * 8 + l];
        uint4_t vx1 = base[(size_t)ix1 * 8 + l];
        uint4_t vy1 = base[(size_t)iy1 * 8 + l];

        // prefetch next pair of indices (branchless, clamped)
        const int i0n = i0 + 2 * ng, i1n = i1 + 2 * ng;
        const int c0n = (i0n < n) ? i0n : 0;
        const int c1n = (i1n < n) ? i1n : 0;
        const int ix0n = x[c0n], iy0n = y[c0n];
        const int ix1n = x[c1n], iy1n = y[c1n];

        float d1a = 0.f, d2a = 0.f, d1b = 0.f, d2b = 0.f;
#pragma unroll
        for (int q = 0; q < 4; ++q) {
            float2_t xlo = __builtin_amdgcn_cvt_pk_f32_fp8(vx0[q], false);
            float2_t xhi = __builtin_amdgcn_cvt_pk_f32_fp8(vx0[q], true);
            float2_t ylo = __builtin_amdgcn_cvt_pk_f32_fp8(vy0[q], false);
            float2_t yhi = __builtin_amdgcn_cvt_pk_f32_fp8(vy0[q], true);
            float h0 = xlo[0] * ylo[0];
            float h1 = xlo[1] * ylo[1];
            float h2 = xhi[0] * yhi[0];
            float h3 = xhi[1] * yhi[1];
            d1a = fmaf(h0, w1f[4 * q + 0], d1a);
            d2a = fmaf(h0, w2f[4 * q + 0], d2a);
            d1a = fmaf(h1, w1f[4 * q + 1], d1a);
            d2a = fmaf(h1, w2f[4 * q + 1], d2a);
            d1a = fmaf(h2, w1f[4 * q + 2], d1a);
            d2a = fmaf(h2, w2f[4 * q + 2], d2a);
            d1a = fmaf(h3, w1f[4 * q + 3], d1a);
            d2a = fmaf(h3, w2f[4 * q + 3], d2a);
        }
#pragma unroll
        for (int q = 0; q < 4; ++q) {
            float2_t xlo = __builtin_amdgcn_cvt_pk_f32_fp8(vx1[q], false);
            float2_t xhi = __builtin_amdgcn_cvt_pk_f32_fp8(vx1[q], true);
            float2_t ylo = __builtin_amdgcn_cvt_pk_f32_fp8(vy1[q], false);
            float2_t yhi = __builtin_amdgcn_cvt_pk_f32_fp8(vy1[q], true);
            float h0 = xlo[0] * ylo[0];
            float h1 = xlo[1] * ylo[1];
            float h2 = xhi[0] * yhi[0];
            float h3 = xhi[1] * yhi[1];
            d1b = fmaf(h0, w1f[4 * q + 0], d1b);
            d2b = fmaf(h0, w2f[4 * q + 0], d2b);
            d1b = fmaf(h1, w1f[4 * q + 1], d1b);
            d2b = fmaf(h1, w2f[4 * q + 1], d2b);
            d1b = fmaf(h2, w1f[4 * q + 2], d1b);
            d2b = fmaf(h2, w2f[4 * q + 2], d2b);
            d1b = fmaf(h3, w1f[4 * q + 3], d1b);
            d2b = fmaf(h3, w2f[4 * q + 3], d2b);
        }
        // butterfly reduce over the 8-lane group; all lanes end with full sums
#pragma unroll
        for (int off = 1; off <= 4; off <<= 1) {
            d1a += __shfl_xor(d1a, off, 64);
            d2a += __shfl_xor(d2a, off, 64);
            d1b += __shfl_xor(d1b, off, 64);
            d2b += __shfl_xor(d2b, off, 64);
        }
        // spread the 4 sigmoid+stores over lanes 0..3
        if (l == 0)                    out[i0]     = sigmoidf_(d1a + bb1);
        else if (l == 1)               out[n + i0] = sigmoidf_(d2a + bb2);
        else if (l == 2 && i1 < n)     out[i1]     = sigmoidf_(d1b + bb1);
        else if (l == 3 && i1 < n)     out[n + i1] = sigmoidf_(d2b + bb2);

        i0 = i0n; i1 = i1n;
        ix0 = ix0n; iy0 = iy0n; ix1 = ix1n; iy1 = iy1n;
    }
}

// Fallback (ws too small for table): gather W columns directly, G=16.
__global__ __launch_bounds__(256) void fused_direct_kernel(
    const int* __restrict__ x, const int* __restrict__ y,
    const float* __restrict__ W, const float* __restrict__ b,
    const float* __restrict__ w1, const float* __restrict__ b1p,
    const float* __restrict__ w2, const float* __restrict__ b2p,
    float* __restrict__ out, int n) {
    const int tid = threadIdx.x;
    const int lane16 = tid & 15;

    float bl[8], w1f[8], w2f[8];
#pragma unroll
    for (int k = 0; k < 8; ++k) {
        bl[k]  = b[lane16 * 8 + k];
        w1f[k] = w1[lane16 * 8 + k];
        w2f[k] = w2[lane16 * 8 + k];
    }
    const float bb1 = *b1p, bb2 = *b2p;

    const int group   = blockIdx.x * (blockDim.x >> 4) + (tid >> 4);
    const int ngroups = gridDim.x * (blockDim.x >> 4);

    for (int i = group; i < n; i += ngroups) {
        const int ix = x[i];
        const int iy = y[i];
        float ex[8], ey[8];
        float ssx = 0.f, ssy = 0.f;
#pragma unroll
        for (int k = 0; k < 8; ++k) {
            int j = lane16 * 8 + k;
            ex[k] = W[(size_t)j * VOCAB + ix] + bl[k];
            ey[k] = W[(size_t)j * VOCAB + iy] + bl[k];
            ssx = fmaf(ex[k], ex[k], ssx);
            ssy = fmaf(ey[k], ey[k], ssy);
        }
#pragma unroll
        for (int off = 8; off >= 1; off >>= 1) {
            ssx += __shfl_xor(ssx, off, 64);
            ssy += __shfl_xor(ssy, off, 64);
        }
        float invx = 1.0f / fmaxf(sqrtf(ssx), EPS);
        float invy = 1.0f / fmaxf(sqrtf(ssy), EPS);

        float d1 = 0.f, d2 = 0.f;
#pragma unroll
        for (int k = 0; k < 8; ++k) {
            float h = (ex[k] * invx) * (ey[k] * invy);
            d1 = fmaf(h, w1f[k], d1);
            d2 = fmaf(h, w2f[k], d2);
        }
#pragma unroll
        for (int off = 8; off >= 1; off >>= 1) {
            d1 += __shfl_xor(d1, off, 64);
            d2 += __shfl_xor(d2, off, 64);
        }
        if (lane16 == 0) {
            out[i]     = sigmoidf_(d1 + bb1);
            out[n + i] = sigmoidf_(d2 + bb2);
        }
    }
}

extern "C" void kernel_launch(void* const* d_in, const int* in_sizes, int n_in,
                              void* d_out, int out_size, void* d_ws, size_t ws_size,
                              hipStream_t stream) {
    const int*   x  = (const int*)d_in[0];
    const int*   y  = (const int*)d_in[1];
    const float* W  = (const float*)d_in[2];
    const float* b  = (const float*)d_in[3];
    const float* w1 = (const float*)d_in[4];
    const float* b1 = (const float*)d_in[5];
    const float* w2 = (const float*)d_in[6];
    const float* b2 = (const float*)d_in[7];
    float* out = (float*)d_out;
    const int n = in_sizes[0];

    const size_t table_bytes = (size_t)VOCAB * EMB;  // fp8: 1 byte/elem = 12.8 MB

    if (ws_size >= table_bytes && n > 0) {
        unsigned int* nt = (unsigned int*)d_ws;
        build_table_fp8_kernel<<<(VOCAB + 255) / 256, 256, 0, stream>>>(W, b, nt);
        // 2048 blocks * 32 groups = 65536 groups; each group does 2 samples/iter
        int blocks = 2048;
        if (n < 2048 * 32) blocks = (n + 31) / 32;
        if (blocks < 1) blocks = 1;
        fused_gather_fp8_kernel<<<blocks, 256, 0, stream>>>(x, y, nt, w1, b1, w2, b2, out, n);
    } else if (n > 0) {
        int ngroups = (n + 15) / 16;
        int blocks  = (ngroups + 15) / 16;
        if (blocks > 8192) blocks = 8192;
        if (blocks < 1) blocks = 1;
        fused_direct_kernel<<<blocks, 256, 0, stream>>>(x, y, W, b, w1, b1, w2, b2, out, n);
    }
}

// Round 4
// 54.549 us; speedup vs baseline: 1.8680x; 1.0074x over previous
//
#include <hip/hip_runtime.h>
#include <hip/hip_bf16.h>
#include <hip/hip_fp16.h>

#define VOCAB 100000
#define EMB 128
#define EPS 1e-12f

typedef __attribute__((ext_vector_type(4))) unsigned int uint4_t;
typedef __attribute__((ext_vector_type(2))) unsigned int uint2_t;
typedef __attribute__((ext_vector_type(2))) float float2_t;

__device__ __forceinline__ float sigmoidf_(float z) {
    return 1.f / (1.f + __expf(-z));
}

#if __has_builtin(__builtin_amdgcn_cvt_scalef32_pk_f32_fp4)
#define HAVE_FP4 1
#else
#define HAVE_FP4 0
#endif

#if HAVE_FP4
// ---------------- fp4 path ----------------
// Table layout: row v = 64 bytes of e2m1 codes (128 x 4b) at nt4 + v*64.
// Per-row scale S (f32) in scl[v]; decoded value = code * S (scale applied
// post-dot: z = Sx*Sy*dot). Decode uses cvt_scalef32_pk_f32_fp4 with scale=1.

__device__ __forceinline__ unsigned int quant_e2m1(float q) {
    float a = fabsf(q);
    unsigned int c = (a > 0.25f) + (a > 0.75f) + (a > 1.25f) + (a > 1.75f) +
                     (a > 2.5f) + (a > 3.5f) + (a > 5.0f);
    return c | ((q < 0.f) ? 8u : 0u);
}

// 4 lanes per column: lane sub handles j in [sub*32, sub*32+32).
__global__ __launch_bounds__(256) void build_table_fp4_kernel(
    const float* __restrict__ W, const float* __restrict__ b,
    unsigned int* __restrict__ nt4, float* __restrict__ scl) {
    const int tid = threadIdx.x;
    const int col = blockIdx.x * 64 + (tid >> 2);
    const int sub = tid & 3;
    if (col >= VOCAB) return;

    float ss = 0.f, mmax = 0.f;
    unsigned int stash[16];
#pragma unroll
    for (int t = 0; t < 16; ++t) {
        int j = sub * 32 + 2 * t;
        float e0 = W[(size_t)j * VOCAB + col] + b[j];
        float e1 = W[(size_t)(j + 1) * VOCAB + col] + b[j + 1];
        ss = fmaf(e0, e0, ss);
        ss = fmaf(e1, e1, ss);
        mmax = fmaxf(mmax, fmaxf(fabsf(e0), fabsf(e1)));
        stash[t] = __builtin_bit_cast(unsigned int, __floats2half2_rn(e0, e1));
    }
    // reduce ss and mmax over the 4-lane quad
    ss += __shfl_xor(ss, 1, 64);
    ss += __shfl_xor(ss, 2, 64);
    mmax = fmaxf(mmax, __shfl_xor(mmax, 1, 64));
    mmax = fmaxf(mmax, __shfl_xor(mmax, 2, 64));

    float inv = 1.0f / fmaxf(sqrtf(ss), EPS);     // normalization
    float nmax = fmaxf(mmax * inv, 1e-30f);       // max |normalized elem|
    float S = nmax * (1.0f / 6.0f);               // decode scale
    float invS = 6.0f / nmax;                     // q = e_norm * invS in [-6,6]

    unsigned int words[4] = {0u, 0u, 0u, 0u};
#pragma unroll
    for (int t = 0; t < 16; ++t) {
        __half2 h2 = __builtin_bit_cast(__half2, stash[t]);
        float q0 = __low2float(h2) * inv * invS;
        float q1 = __high2float(h2) * inv * invS;
        unsigned int c0 = quant_e2m1(q0);
        unsigned int c1 = quant_e2m1(q1);
        words[t >> 2] |= (c0 << (8 * (t & 3))) | (c1 << (8 * (t & 3) + 4));
    }
    uint4_t pk;
    pk[0] = words[0]; pk[1] = words[1]; pk[2] = words[2]; pk[3] = words[3];
    *(uint4_t*)(nt4 + (size_t)col * 16 + sub * 4) = pk;
    if (sub == 0) scl[col] = S;
}

#define CVT4(u, s) __builtin_amdgcn_cvt_scalef32_pk_f32_fp4((u), 1.0f, (s))

// 8 lanes per sample; lane l owns elems [16l,16l+16) = 8 bytes of the row.
// 2 samples per iteration + index prefetch.
__global__ __launch_bounds__(256) void fused_gather_fp4_kernel(
    const int* __restrict__ x, const int* __restrict__ y,
    const unsigned int* __restrict__ nt4, const float* __restrict__ scl,
    const float* __restrict__ w1, const float* __restrict__ b1p,
    const float* __restrict__ w2, const float* __restrict__ b2p,
    float* __restrict__ out, int n) {
    const int tid = threadIdx.x;
    const int l = tid & 7;
    const int group = blockIdx.x * 32 + (tid >> 3);
    const int ng = gridDim.x * 32;

    // float2 weights for lane's 16 elems
    float2_t w1v[8], w2v[8];
    const float2_t* w1p = (const float2_t*)w1;
    const float2_t* w2p = (const float2_t*)w2;
#pragma unroll
    for (int q = 0; q < 8; ++q) {
        w1v[q] = w1p[l * 8 + q];
        w2v[q] = w2p[l * 8 + q];
    }
    const float bb1 = *b1p, bb2 = *b2p;

    const uint2_t* base = (const uint2_t*)nt4;  // row v = base[v*8 + l]

    int i0 = group, i1 = group + ng;
    int c0 = (i0 < n) ? i0 : 0;
    int c1 = (i1 < n) ? i1 : 0;
    int ix0 = x[c0], iy0 = y[c0];
    int ix1 = x[c1], iy1 = y[c1];

    while (i0 < n) {
        uint2_t rx0 = base[(size_t)ix0 * 8 + l];
        uint2_t ry0 = base[(size_t)iy0 * 8 + l];
        uint2_t rx1 = base[(size_t)ix1 * 8 + l];
        uint2_t ry1 = base[(size_t)iy1 * 8 + l];
        float sx0 = scl[ix0], sy0 = scl[iy0];
        float sx1 = scl[ix1], sy1 = scl[iy1];

        const int i0n = i0 + 2 * ng, i1n = i1 + 2 * ng;
        const int c0n = (i0n < n) ? i0n : 0;
        const int c1n = (i1n < n) ? i1n : 0;
        const int ix0n = x[c0n], iy0n = y[c0n];
        const int ix1n = x[c1n], iy1n = y[c1n];

        float2_t a1 = {0.f, 0.f}, a2 = {0.f, 0.f};
        float2_t e1v = {0.f, 0.f}, e2v = {0.f, 0.f};
        {
            float2_t h;
            h = CVT4(rx0[0], 0) * CVT4(ry0[0], 0); a1 += h * w1v[0]; a2 += h * w2v[0];
            h = CVT4(rx0[0], 1) * CVT4(ry0[0], 1); a1 += h * w1v[1]; a2 += h * w2v[1];
            h = CVT4(rx0[0], 2) * CVT4(ry0[0], 2); a1 += h * w1v[2]; a2 += h * w2v[2];
            h = CVT4(rx0[0], 3) * CVT4(ry0[0], 3); a1 += h * w1v[3]; a2 += h * w2v[3];
            h = CVT4(rx0[1], 0) * CVT4(ry0[1], 0); a1 += h * w1v[4]; a2 += h * w2v[4];
            h = CVT4(rx0[1], 1) * CVT4(ry0[1], 1); a1 += h * w1v[5]; a2 += h * w2v[5];
            h = CVT4(rx0[1], 2) * CVT4(ry0[1], 2); a1 += h * w1v[6]; a2 += h * w2v[6];
            h = CVT4(rx0[1], 3) * CVT4(ry0[1], 3); a1 += h * w1v[7]; a2 += h * w2v[7];
            h = CVT4(rx1[0], 0) * CVT4(ry1[0], 0); e1v += h * w1v[0]; e2v += h * w2v[0];
            h = CVT4(rx1[0], 1) * CVT4(ry1[0], 1); e1v += h * w1v[1]; e2v += h * w2v[1];
            h = CVT4(rx1[0], 2) * CVT4(ry1[0], 2); e1v += h * w1v[2]; e2v += h * w2v[2];
            h = CVT4(rx1[0], 3) * CVT4(ry1[0], 3); e1v += h * w1v[3]; e2v += h * w2v[3];
            h = CVT4(rx1[1], 0) * CVT4(ry1[1], 0); e1v += h * w1v[4]; e2v += h * w2v[4];
            h = CVT4(rx1[1], 1) * CVT4(ry1[1], 1); e1v += h * w1v[5]; e2v += h * w2v[5];
            h = CVT4(rx1[1], 2) * CVT4(ry1[1], 2); e1v += h * w1v[6]; e2v += h * w2v[6];
            h = CVT4(rx1[1], 3) * CVT4(ry1[1], 3); e1v += h * w1v[7]; e2v += h * w2v[7];
        }
        float d1a = a1[0] + a1[1], d2a = a2[0] + a2[1];
        float d1b = e1v[0] + e1v[1], d2b = e2v[0] + e2v[1];
#pragma unroll
        for (int off = 1; off <= 4; off <<= 1) {
            d1a += __shfl_xor(d1a, off, 64);
            d2a += __shfl_xor(d2a, off, 64);
            d1b += __shfl_xor(d1b, off, 64);
            d2b += __shfl_xor(d2b, off, 64);
        }
        const float sa = sx0 * sy0, sb = sx1 * sy1;
        if (l == 0)                out[i0]     = sigmoidf_(fmaf(d1a, sa, bb1));
        else if (l == 1)           out[n + i0] = sigmoidf_(fmaf(d2a, sa, bb2));
        else if (l == 2 && i1 < n) out[i1]     = sigmoidf_(fmaf(d1b, sb, bb1));
        else if (l == 3 && i1 < n) out[n + i1] = sigmoidf_(fmaf(d2b, sb, bb2));

        i0 = i0n; i1 = i1n;
        ix0 = ix0n; iy0 = iy0n; ix1 = ix1n; iy1 = iy1n;
    }
}
#endif  // HAVE_FP4

// ---------------- fp8 path (proven round-3 fallback) ----------------
__device__ __forceinline__ unsigned int f2bf_(float f) {
    __hip_bfloat16 h = __float2bfloat16(f);
    return (unsigned int)__builtin_bit_cast(unsigned short, h);
}

__global__ __launch_bounds__(256) void build_table_fp8_kernel(
    const float* __restrict__ W, const float* __restrict__ b,
    unsigned int* __restrict__ nt) {
    int v = blockIdx.x * 256 + threadIdx.x;
    if (v >= VOCAB) return;

    float ss = 0.f;
    unsigned int stash[64];
#pragma unroll
    for (int j = 0; j < 64; ++j) {
        float e0 = W[(size_t)(2 * j) * VOCAB + v] + b[2 * j];
        float e1 = W[(size_t)(2 * j + 1) * VOCAB + v] + b[2 * j + 1];
        ss = fmaf(e0, e0, ss);
        ss = fmaf(e1, e1, ss);
        stash[j] = __builtin_bit_cast(unsigned int, __floats2half2_rn(e0, e1));
    }
    float inv = 1.0f / fmaxf(sqrtf(ss), EPS);

    unsigned int packed[32];
#pragma unroll
    for (int j = 0; j < 32; ++j) {
        __half2 h0 = __builtin_bit_cast(__half2, stash[2 * j]);
        __half2 h1 = __builtin_bit_cast(__half2, stash[2 * j + 1]);
        float e0 = __low2float(h0) * inv, e1 = __high2float(h0) * inv;
        float e2 = __low2float(h1) * inv, e3 = __high2float(h1) * inv;
        unsigned int u = __builtin_amdgcn_cvt_pk_fp8_f32(e0, e1, 0u, false);
        u = __builtin_amdgcn_cvt_pk_fp8_f32(e2, e3, u, true);
        packed[j] = u;
    }
    uint4_t* row = (uint4_t*)(nt + (size_t)v * 32);
#pragma unroll
    for (int q = 0; q < 8; ++q) {
        uint4_t pk;
        pk[0] = packed[4 * q + 0];
        pk[1] = packed[4 * q + 1];
        pk[2] = packed[4 * q + 2];
        pk[3] = packed[4 * q + 3];
        row[q] = pk;
    }
}

__global__ __launch_bounds__(256) void fused_gather_fp8_kernel(
    const int* __restrict__ x, const int* __restrict__ y,
    const unsigned int* __restrict__ nt,
    const float* __restrict__ w1, const float* __restrict__ b1p,
    const float* __restrict__ w2, const float* __restrict__ b2p,
    float* __restrict__ out, int n) {
    const int tid = threadIdx.x;
    const int l = tid & 7;
    const int group = blockIdx.x * 32 + (tid >> 3);
    const int ng = gridDim.x * 32;

    float w1f[16], w2f[16];
#pragma unroll
    for (int k = 0; k < 16; ++k) {
        w1f[k] = w1[l * 16 + k];
        w2f[k] = w2[l * 16 + k];
    }
    const float bb1 = *b1p, bb2 = *b2p;
    const uint4_t* base = (const uint4_t*)nt;

    int i0 = group, i1 = group + ng;
    int c0 = (i0 < n) ? i0 : 0;
    int c1 = (i1 < n) ? i1 : 0;
    int ix0 = x[c0], iy0 = y[c0];
    int ix1 = x[c1], iy1 = y[c1];

    while (i0 < n) {
        uint4_t vx0 = base[(size_t)ix0 * 8 + l];
        uint4_t vy0 = base[(size_t)iy0 * 8 + l];
        uint4_t vx1 = base[(size_t)ix1 * 8 + l];
        uint4_t vy1 = base[(size_t)iy1 * 8 + l];

        const int i0n = i0 + 2 * ng, i1n = i1 + 2 * ng;
        const int c0n = (i0n < n) ? i0n : 0;
        const int c1n = (i1n < n) ? i1n : 0;
        const int ix0n = x[c0n], iy0n = y[c0n];
        const int ix1n = x[c1n], iy1n = y[c1n];

        float d1a = 0.f, d2a = 0.f, d1b = 0.f, d2b = 0.f;
#pragma unroll
        for (int q = 0; q < 4; ++q) {
            float2_t xlo = __builtin_amdgcn_cvt_pk_f32_fp8(vx0[q], false);
            float2_t xhi = __builtin_amdgcn_cvt_pk_f32_fp8(vx0[q], true);
            float2_t ylo = __builtin_amdgcn_cvt_pk_f32_fp8(vy0[q], false);
            float2_t yhi = __builtin_amdgcn_cvt_pk_f32_fp8(vy0[q], true);
            float h0 = xlo[0] * ylo[0];
            float h1 = xlo[1] * ylo[1];
            float h2 = xhi[0] * yhi[0];
            float h3 = xhi[1] * yhi[1];
            d1a = fmaf(h0, w1f[4 * q + 0], d1a);
            d2a = fmaf(h0, w2f[4 * q + 0], d2a);
            d1a = fmaf(h1, w1f[4 * q + 1], d1a);
            d2a = fmaf(h1, w2f[4 * q + 1], d2a);
            d1a = fmaf(h2, w1f[4 * q + 2], d1a);
            d2a = fmaf(h2, w2f[4 * q + 2], d2a);
            d1a = fmaf(h3, w1f[4 * q + 3], d1a);
            d2a = fmaf(h3, w2f[4 * q + 3], d2a);
        }
#pragma unroll
        for (int q = 0; q < 4; ++q) {
            float2_t xlo = __builtin_amdgcn_cvt_pk_f32_fp8(vx1[q], false);
            float2_t xhi = __builtin_amdgcn_cvt_pk_f32_fp8(vx1[q], true);
            float2_t ylo = __builtin_amdgcn_cvt_pk_f32_fp8(vy1[q], false);
            float2_t yhi = __builtin_amdgcn_cvt_pk_f32_fp8(vy1[q], true);
            float h0 = xlo[0] * ylo[0];
            float h1 = xlo[1] * ylo[1];
            float h2 = xhi[0] * yhi[0];
            float h3 = xhi[1] * yhi[1];
            d1b = fmaf(h0, w1f[4 * q + 0], d1b);
            d2b = fmaf(h0, w2f[4 * q + 0], d2b);
            d1b = fmaf(h1, w1f[4 * q + 1], d1b);
            d2b = fmaf(h1, w2f[4 * q + 1], d2b);
            d1b = fmaf(h2, w1f[4 * q + 2], d1b);
            d2b = fmaf(h2, w2f[4 * q + 2], d2b);
            d1b = fmaf(h3, w1f[4 * q + 3], d1b);
            d2b = fmaf(h3, w2f[4 * q + 3], d2b);
        }
#pragma unroll
        for (int off = 1; off <= 4; off <<= 1) {
            d1a += __shfl_xor(d1a, off, 64);
            d2a += __shfl_xor(d2a, off, 64);
            d1b += __shfl_xor(d1b, off, 64);
            d2b += __shfl_xor(d2b, off, 64);
        }
        if (l == 0)                out[i0]     = sigmoidf_(d1a + bb1);
        else if (l == 1)           out[n + i0] = sigmoidf_(d2a + bb2);
        else if (l == 2 && i1 < n) out[i1]     = sigmoidf_(d1b + bb1);
        else if (l == 3 && i1 < n) out[n + i1] = sigmoidf_(d2b + bb2);

        i0 = i0n; i1 = i1n;
        ix0 = ix0n; iy0 = iy0n; ix1 = ix1n; iy1 = iy1n;
    }
}

// Fallback (ws too small for any table): gather W columns directly, G=16.
__global__ __launch_bounds__(256) void fused_direct_kernel(
    const int* __restrict__ x, const int* __restrict__ y,
    const float* __restrict__ W, const float* __restrict__ b,
    const float* __restrict__ w1, const float* __restrict__ b1p,
    const float* __restrict__ w2, const float* __restrict__ b2p,
    float* __restrict__ out, int n) {
    const int tid = threadIdx.x;
    const int lane16 = tid & 15;

    float bl[8], w1f[8], w2f[8];
#pragma unroll
    for (int k = 0; k < 8; ++k) {
        bl[k]  = b[lane16 * 8 + k];
        w1f[k] = w1[lane16 * 8 + k];
        w2f[k] = w2[lane16 * 8 + k];
    }
    const float bb1 = *b1p, bb2 = *b2p;

    const int group   = blockIdx.x * (blockDim.x >> 4) + (tid >> 4);
    const int ngroups = gridDim.x * (blockDim.x >> 4);

    for (int i = group; i < n; i += ngroups) {
        const int ix = x[i];
        const int iy = y[i];
        float ex[8], ey[8];
        float ssx = 0.f, ssy = 0.f;
#pragma unroll
        for (int k = 0; k < 8; ++k) {
            int j = lane16 * 8 + k;
            ex[k] = W[(size_t)j * VOCAB + ix] + bl[k];
            ey[k] = W[(size_t)j * VOCAB + iy] + bl[k];
            ssx = fmaf(ex[k], ex[k], ssx);
            ssy = fmaf(ey[k], ey[k], ssy);
        }
#pragma unroll
        for (int off = 8; off >= 1; off >>= 1) {
            ssx += __shfl_xor(ssx, off, 64);
            ssy += __shfl_xor(ssy, off, 64);
        }
        float invx = 1.0f / fmaxf(sqrtf(ssx), EPS);
        float invy = 1.0f / fmaxf(sqrtf(ssy), EPS);

        float d1 = 0.f, d2 = 0.f;
#pragma unroll
        for (int k = 0; k < 8; ++k) {
            float h = (ex[k] * invx) * (ey[k] * invy);
            d1 = fmaf(h, w1f[k], d1);
            d2 = fmaf(h, w2f[k], d2);
        }
#pragma unroll
        for (int off = 8; off >= 1; off >>= 1) {
            d1 += __shfl_xor(d1, off, 64);
            d2 += __shfl_xor(d2, off, 64);
        }
        if (lane16 == 0) {
            out[i]     = sigmoidf_(d1 + bb1);
            out[n + i] = sigmoidf_(d2 + bb2);
        }
    }
}

extern "C" void kernel_launch(void* const* d_in, const int* in_sizes, int n_in,
                              void* d_out, int out_size, void* d_ws, size_t ws_size,
                              hipStream_t stream) {
    const int*   x  = (const int*)d_in[0];
    const int*   y  = (const int*)d_in[1];
    const float* W  = (const float*)d_in[2];
    const float* b  = (const float*)d_in[3];
    const float* w1 = (const float*)d_in[4];
    const float* b1 = (const float*)d_in[5];
    const float* w2 = (const float*)d_in[6];
    const float* b2 = (const float*)d_in[7];
    float* out = (float*)d_out;
    const int n = in_sizes[0];
    if (n <= 0) return;

#if HAVE_FP4
    const size_t fp4_bytes = (size_t)VOCAB * 64 + (size_t)VOCAB * 4;  // table + scales
    if (ws_size >= fp4_bytes) {
        unsigned int* nt4 = (unsigned int*)d_ws;
        float* scl = (float*)((char*)d_ws + (size_t)VOCAB * 64);
        build_table_fp4_kernel<<<(VOCAB + 63) / 64, 256, 0, stream>>>(W, b, nt4, scl);
        int blocks = 2048;
        if (n < 2048 * 32) blocks = (n + 31) / 32;
        if (blocks < 1) blocks = 1;
        fused_gather_fp4_kernel<<<blocks, 256, 0, stream>>>(x, y, nt4, scl, w1, b1, w2, b2, out, n);
        return;
    }
#endif
    const size_t fp8_bytes = (size_t)VOCAB * EMB;
    if (ws_size >= fp8_bytes) {
        unsigned int* nt = (unsigned int*)d_ws;
        build_table_fp8_kernel<<<(VOCAB + 255) / 256, 256, 0, stream>>>(W, b, nt);
        int blocks = 2048;
        if (n < 2048 * 32) blocks = (n + 31) / 32;
        if (blocks < 1) blocks = 1;
        fused_gather_fp8_kernel<<<blocks, 256, 0, stream>>>(x, y, nt, w1, b1, w2, b2, out, n);
    } else {
        int ngroups = (n + 15) / 16;
        int blocks  = (ngroups + 15) / 16;
        if (blocks > 8192) blocks = 8192;
        if (blocks < 1) blocks = 1;
        fused_direct_kernel<<<blocks, 256, 0, stream>>>(x, y, W, b, w1, b1, w2, b2, out, n);
    }
}